// Round 8
// baseline (587.819 us; speedup 1.0000x reference)
//
#include <hip/hip_runtime.h>

// out[b,y,x] = sum_c sum_{p,q} feat1[b,c,y+p-2,x+q-2] * feat2[b,c,p,q]
// B=4096, C=512, H=W=4.
//
// R7 post-mortem: lambda->macro changed NOTHING (bit-identical WRITE 500MB,
// VGPR 64) -> culprit is the t-indexed 2D arrays (wr/racc) in the body:
// if the inner t-loop doesn't unroll they're runtime-indexed -> scratch
// (rule #20). This version: FULL SCALARIZATION — named scalars r00..r33,
// weight rows consumed as .x/.y/.z/.w directly. No arrays between load and
// butterfly (butterfly's v16/wtmp measured clean in R2/R4).

__device__ __forceinline__ float4 shflx4(float4 v, int m) {
    float4 r;
    r.x = __shfl_xor(v.x, m, 64);
    r.y = __shfl_xor(v.y, m, 64);
    r.z = __shfl_xor(v.z, m, 64);
    r.w = __shfl_xor(v.w, m, 64);
    return r;
}

// Row-correlation of a-row (a0..a3) with w-row W (float4), accumulated into
// the four named scalars rx0..rx3 (out columns x=0..3). OOB terms dropped:
//   x=0: kk=2,3 -> a0,a1   x=1: kk=1,2,3 -> a0,a1,a2
//   x=2: kk=0..3 -> a0..a3 x=3: kk=0,1,2 -> a1,a2,a3
#define ROWCORR(rx0, rx1, rx2, rx3, a0, a1, a2, a3, W)                      \
    rx0 = fmaf((a0), (W).z, rx0);                                           \
    rx0 = fmaf((a1), (W).w, rx0);                                           \
    rx1 = fmaf((a0), (W).y, rx1);                                           \
    rx1 = fmaf((a1), (W).z, rx1);                                           \
    rx1 = fmaf((a2), (W).w, rx1);                                           \
    rx2 = fmaf((a0), (W).x, rx2);                                           \
    rx2 = fmaf((a1), (W).y, rx2);                                           \
    rx2 = fmaf((a2), (W).z, rx2);                                           \
    rx2 = fmaf((a3), (W).w, rx2);                                           \
    rx3 = fmaf((a1), (W).x, rx3);                                           \
    rx3 = fmaf((a2), (W).y, rx3);                                           \
    rx3 = fmaf((a3), (W).z, rx3);

// One chunk: this lane's a-row vs all 4 w-rows of its channel (t = xor dist).
#define CORR_BODY(Av, Wv)                                                   \
    do {                                                                    \
        const float4 w1v = shflx4((Wv), 1);                                 \
        const float4 w2v = shflx4((Wv), 2);                                 \
        const float4 w3v = shflx4((Wv), 3);                                 \
        const float a0 = (Av).x, a1 = (Av).y, a2 = (Av).z, a3 = (Av).w;     \
        ROWCORR(r00, r01, r02, r03, a0, a1, a2, a3, (Wv))                   \
        ROWCORR(r10, r11, r12, r13, a0, a1, a2, a3, w1v)                    \
        ROWCORR(r20, r21, r22, r23, a0, a1, a2, a3, w2v)                    \
        ROWCORR(r30, r31, r32, r33, a0, a1, a2, a3, w3v)                    \
    } while (0)

__global__ __launch_bounds__(256, 4) void corr_kernel(
        const float4* __restrict__ feat1,
        const float4* __restrict__ feat2,
        float* __restrict__ out) {
    const int tid  = threadIdx.x;
    const int lane = tid & 63;
    const int wv   = tid >> 6;                 // 0..3
    const int b    = blockIdx.x * 2 + (wv >> 1);
    const int half = wv & 1;                   // which half of the channels
    const int u    = lane & 3;                 // row (h) this lane owns

    // float4-unit base: lane i -> consecutive float4 (perfectly coalesced)
    const size_t kbase = (size_t)b * 2048 + (size_t)half * 1024 + lane;

    // accumulators: r{t}{x}, t = w-row xor distance, x = out column
    float r00 = 0.f, r01 = 0.f, r02 = 0.f, r03 = 0.f;
    float r10 = 0.f, r11 = 0.f, r12 = 0.f, r13 = 0.f;
    float r20 = 0.f, r21 = 0.f, r22 = 0.f, r23 = 0.f;
    float r30 = 0.f, r31 = 0.f, r32 = 0.f, r33 = 0.f;

    float4 A0 = feat1[kbase];
    float4 W0 = feat2[kbase];
    float4 A1, W1;

    #pragma unroll
    for (int j = 0; j < 16; j += 2) {          // 16 chunks x 64 float4
        A1 = feat1[kbase + (size_t)(j + 1) * 64];
        W1 = feat2[kbase + (size_t)(j + 1) * 64];
        __builtin_amdgcn_sched_barrier(0);     // keep prefetch above compute
        CORR_BODY(A0, W0);
        if (j + 2 < 16) {
            A0 = feat1[kbase + (size_t)(j + 2) * 64];
            W0 = feat2[kbase + (size_t)(j + 2) * 64];
        }
        __builtin_amdgcn_sched_barrier(0);
        CORR_BODY(A1, W1);
    }

    // Per-lane remap: r{t}· = rowcorr(a_u, w_p), p=u^t, belongs to out-row
    // y = u-p+2. Enumerated per u (12 valid (u,p) pairs; verified R4-R7):
    //   y=2: t=0 all u.  y=1: u0,u2 <- t1; u1 <- t3.
    //   y=3: u1,u3 <- t1; u2 <- t3.  y=0: u0,u1 <- t2.
    const bool y1t1 = (u == 0 || u == 2), y1t3 = (u == 1);
    const bool y3t1 = (u == 1 || u == 3), y3t3 = (u == 2);
    const bool y0t2 = (u < 2);

    float v16[16];
    v16[8]  = r00; v16[9]  = r01; v16[10] = r02; v16[11] = r03;
    v16[4]  = y1t1 ? r10 : (y1t3 ? r30 : 0.f);
    v16[5]  = y1t1 ? r11 : (y1t3 ? r31 : 0.f);
    v16[6]  = y1t1 ? r12 : (y1t3 ? r32 : 0.f);
    v16[7]  = y1t1 ? r13 : (y1t3 ? r33 : 0.f);
    v16[12] = y3t1 ? r10 : (y3t3 ? r30 : 0.f);
    v16[13] = y3t1 ? r11 : (y3t3 ? r31 : 0.f);
    v16[14] = y3t1 ? r12 : (y3t3 ? r32 : 0.f);
    v16[15] = y3t1 ? r13 : (y3t3 ? r33 : 0.f);
    v16[0]  = y0t2 ? r20 : 0.f;
    v16[1]  = y0t2 ? r21 : 0.f;
    v16[2]  = y0t2 ? r22 : 0.f;
    v16[3]  = y0t2 ? r23 : 0.f;

    // Value-splitting butterfly (measured clean + correct in R2/R4): after
    // 4 steps lane l holds component (l&15) summed over its 16-lane group;
    // 2 xor steps finish the wave.
    #pragma unroll
    for (int k = 0; k < 4; ++k) {
        const int m = 1 << k;
        const int pairs = 8 >> k;
        const bool sel = (lane >> k) & 1;
        float wtmp[8];
        #pragma unroll
        for (int p = 0; p < pairs; ++p) {
            float keep = sel ? v16[2 * p + 1] : v16[2 * p];
            float send = sel ? v16[2 * p]     : v16[2 * p + 1];
            float recv = __shfl_xor(send, m, 64);
            wtmp[p] = keep + recv;
        }
        #pragma unroll
        for (int p = 0; p < pairs; ++p) v16[p] = wtmp[p];
    }
    float r = v16[0];
    r += __shfl_xor(r, 16, 64);
    r += __shfl_xor(r, 32, 64);
    // lane l holds component (l&15) of this wave's half-channel partial sum

    __shared__ float red[4][16];
    if (lane < 16) red[wv][lane] = r;
    __syncthreads();
    if (tid < 32) {                            // combine halves, store 2 b's
        const int bs   = tid >> 4;
        const int comp = tid & 15;
        const float s = red[bs * 2 + 0][comp] + red[bs * 2 + 1][comp];
        out[(size_t)(blockIdx.x * 2 + bs) * 16 + comp] = s;
    }
}

extern "C" void kernel_launch(void* const* d_in, const int* in_sizes, int n_in,
                              void* d_out, int out_size, void* d_ws, size_t ws_size,
                              hipStream_t stream) {
    const float4* feat1 = (const float4*)d_in[0];
    const float4* feat2 = (const float4*)d_in[1];
    float* out = (float*)d_out;
    const int B = in_sizes[0] / (512 * 16);    // 4096
    corr_kernel<<<dim3(B / 2), dim3(256), 0, stream>>>(feat1, feat2, out);
}